// Round 9
// baseline (174.654 us; speedup 1.0000x reference)
//
#include <hip/hip_runtime.h>
#include <math.h>

// Problem constants
static constexpr int Bv  = 2;
static constexpr int Ncam= 6;
static constexpr int Cch = 256;
static constexpr int Hh  = 56;
static constexpr int Ww  = 100;
static constexpr int Pn  = Hh * Ww;  // 5600 flat pixels
static constexpr int Qn  = 900;
static constexpr int En  = 256;
static constexpr int NH  = 8;
static constexpr int HD  = 32;   // E / NH

typedef _Float16 f16x8 __attribute__((ext_vector_type(8)));
typedef _Float16 f16x4 __attribute__((ext_vector_type(4)));
typedef _Float16 f16x2 __attribute__((ext_vector_type(2)));
typedef float    f32x4 __attribute__((ext_vector_type(4)));

// ---------------------------------------------------------------------------
// K0: weight pack only (4 matrices fp32[K][N] -> f16[N][K]). 256 blocks.
// ---------------------------------------------------------------------------
__global__ __launch_bounds__(256)
void wpack_kernel(const float* __restrict__ W0, const float* __restrict__ W1,
                  const float* __restrict__ W2, const float* __restrict__ W3,
                  _Float16* __restrict__ wt_out) {
    __shared__ float tile[32][33];
    int bid = blockIdx.x;
    int t = threadIdx.x;
    int z = bid >> 6, rem = bid & 63;
    const float* src = (z == 0) ? W0 : (z == 1) ? W1 : (z == 2) ? W2 : W3;
    int k0 = (rem & 7) * 32, n0 = (rem >> 3) * 32;
    int tx = t & 31, ty = t >> 5;  // 32 x 8
    for (int i = 0; i < 32; i += 8)
        tile[ty + i][tx] = src[(size_t)(k0 + ty + i) * 256 + n0 + tx];
    __syncthreads();
    _Float16* dst = wt_out + (size_t)z * 256 * 256;
    for (int i = 0; i < 32; i += 8)
        dst[(size_t)(n0 + ty + i) * 256 + k0 + tx] = (_Float16)tile[tx][ty + i];
}

// ---------------------------------------------------------------------------
// K3: fused ref3d + projection + bilinear sample + masked mean + add qe.
// One block per (b,q), 256 threads = channels. Each block computes its own
// ref3d (256x3 dot, block-reduced) and the 12 wave-uniform projections —
// no gridbuf, no serialized prelude dependency. Block (b==0) also writes
// the ref3d output rows (identical for both batches).
// ---------------------------------------------------------------------------
__global__ __launch_bounds__(256)
void sample_kernel(const float* __restrict__ feats,
                   const float* __restrict__ qt,
                   const float* __restrict__ refW,
                   const float* __restrict__ refb,
                   const float* __restrict__ l2i,
                   _Float16* __restrict__ xbuf,
                   float* __restrict__ out_ref3d) {
    __shared__ float red[4][3];
    int bq = blockIdx.x;
    int b = bq / Qn, q = bq % Qn;
    int t = threadIdx.x;
    int wave = t >> 6, lane = t & 63;
    int c = t;

    // ---- ref3d: 256x3 dot + sigmoid ----
    float a = qt[(size_t)q * En + c];
    float s0 = a * refW[c * 3 + 0];
    float s1 = a * refW[c * 3 + 1];
    float s2 = a * refW[c * 3 + 2];
    #pragma unroll
    for (int off = 32; off >= 1; off >>= 1) {
        s0 += __shfl_xor(s0, off, 64);
        s1 += __shfl_xor(s1, off, 64);
        s2 += __shfl_xor(s2, off, 64);
    }
    if (lane == 0) { red[wave][0] = s0; red[wave][1] = s1; red[wave][2] = s2; }
    __syncthreads();
    float v0 = red[0][0] + red[1][0] + red[2][0] + red[3][0];
    float v1 = red[0][1] + red[1][1] + red[2][1] + red[3][1];
    float v2 = red[0][2] + red[1][2] + red[2][2] + red[3][2];
    v0 = 1.f / (1.f + __expf(-(v0 + refb[0])));
    v1 = 1.f / (1.f + __expf(-(v1 + refb[1])));
    v2 = 1.f / (1.f + __expf(-(v2 + refb[2])));
    if (b == 0 && t < 3) {
        float rv = (t == 0) ? v0 : (t == 1) ? v1 : v2;
        out_ref3d[(size_t)q * 3 + t] = rv;
        out_ref3d[(size_t)(Qn + q) * 3 + t] = rv;
    }

    // ---- per-camera projection (wave-uniform) + gather ----
    float acc = 0.f, cnt = 0.f;
    for (int n = 0; n < Ncam; n++) {
        const float* M = l2i + (size_t)(b * Ncam + n) * 16;
        float p0 = M[0] * v0 + M[1] * v1 + M[2]  * v2 + M[3];
        float p1 = M[4] * v0 + M[5] * v1 + M[6]  * v2 + M[7];
        float z  = M[8] * v0 + M[9] * v1 + M[10] * v2 + M[11];
        float denom = fabsf(z) + 1e-5f;
        float px = p0 / denom, py = p1 / denom;
        float gx = px / (float)(Ww - 1) * 2.f - 1.f;
        float gy = py / (float)(Hh - 1) * 2.f - 1.f;
        bool zm = z > 1e-5f;
        bool valid = (gx > -1.f) && (gx < 1.f) && (gy > -1.f) && (gy < 1.f);
        if (zm && valid) {
            cnt += 1.f;
            float x = ((gx + 1.f) * (float)Ww - 1.f) * 0.5f;
            float y = ((gy + 1.f) * (float)Hh - 1.f) * 0.5f;
            float x0f = floorf(x), y0f = floorf(y);
            int x0 = (int)x0f, y0 = (int)y0f;
            float wx1 = x - x0f, wx0 = 1.f - wx1;
            float wy1 = y - y0f, wy0 = 1.f - wy1;
            const float* base = feats + ((size_t)(b * Ncam + n) * Cch + c) * Pn;
            // wave-uniform interior test
            if (x0 >= 0 && x0 + 1 < Ww && y0 >= 0 && y0 + 1 < Hh) {
                const float* r0 = base + (size_t)y0 * Ww + x0;
                const float* r1 = r0 + Ww;
                acc += r0[0] * (wx0 * wy0) + r0[1] * (wx1 * wy0)
                     + r1[0] * (wx0 * wy1) + r1[1] * (wx1 * wy1);
            } else {
                bool xin0 = (x0 >= 0) & (x0 < Ww), xin1 = (x0 + 1 >= 0) & (x0 + 1 < Ww);
                bool yin0 = (y0 >= 0) & (y0 < Hh), yin1 = (y0 + 1 >= 0) & (y0 + 1 < Hh);
                if (xin0 & yin0) acc += base[(size_t)y0 * Ww + x0]           * (wx0 * wy0);
                if (xin1 & yin0) acc += base[(size_t)y0 * Ww + x0 + 1]       * (wx1 * wy0);
                if (xin0 & yin1) acc += base[(size_t)(y0 + 1) * Ww + x0]     * (wx0 * wy1);
                if (xin1 & yin1) acc += base[(size_t)(y0 + 1) * Ww + x0 + 1] * (wx1 * wy1);
            }
        }
    }
    float tgt = acc / fmaxf(cnt, 1.f);
    xbuf[(size_t)bq * En + c] = (_Float16)(qt[(size_t)q * En + c] + tgt);
}

// ---------------------------------------------------------------------------
// K4: MFMA f16 GEMM body (64x64 tile): C = A @ Wt + bias; f16 or f32 out.
// ---------------------------------------------------------------------------
__device__ __forceinline__ void mfma_gemm_body(const _Float16* __restrict__ A,
                                               const _Float16* __restrict__ Wt,
                                               const float* __restrict__ bias,
                                               _Float16* __restrict__ Cf16,
                                               float* __restrict__ Cf32,
                                               int M, int m0, int n0) {
    __shared__ _Float16 Ws[64][264];
    int t = threadIdx.x;
    int wave = t >> 6, lane = t & 63, quad = lane >> 4, col = lane & 15;
    {
        int row = t >> 5;
        int off = (t & 31) * 8;
        for (int i = 0; i < 8; i++)
            *(f16x8*)&Ws[row + i * 8][off] =
                *(const f16x8*)&Wt[(size_t)(n0 + row + i * 8) * 256 + off];
    }
    f16x8 af[8];
    int mrow = m0 + wave * 16 + col;
    if (mrow < M) {
        const _Float16* ap = A + (size_t)mrow * 256 + quad * 8;
        #pragma unroll
        for (int kc = 0; kc < 8; kc++) af[kc] = *(const f16x8*)(ap + kc * 32);
    } else {
        #pragma unroll
        for (int kc = 0; kc < 8; kc++)
            #pragma unroll
            for (int j = 0; j < 8; j++) af[kc][j] = (_Float16)0.f;
    }
    __syncthreads();
    f32x4 acc[4];
    #pragma unroll
    for (int nt = 0; nt < 4; nt++) { acc[nt][0]=0.f; acc[nt][1]=0.f; acc[nt][2]=0.f; acc[nt][3]=0.f; }
    #pragma unroll
    for (int nt = 0; nt < 4; nt++)
        #pragma unroll
        for (int kc = 0; kc < 8; kc++) {
            f16x8 bf = *(const f16x8*)&Ws[nt * 16 + col][kc * 32 + quad * 8];
            acc[nt] = __builtin_amdgcn_mfma_f32_16x16x32_f16(af[kc], bf, acc[nt], 0, 0, 0);
        }
    #pragma unroll
    for (int nt = 0; nt < 4; nt++) {
        int n = n0 + nt * 16 + col;
        float bv = bias[n];
        #pragma unroll
        for (int r = 0; r < 4; r++) {
            int m = m0 + wave * 16 + quad * 4 + r;
            if (m < M) {
                float v = acc[nt][r] + bv;
                if (Cf16) Cf16[(size_t)m * 256 + n] = (_Float16)v;
                else      Cf32[(size_t)m * 256 + n] = v;
            }
        }
    }
}

__global__ __launch_bounds__(256)
void qkv_mfma_kernel(const _Float16* __restrict__ A,
                     const _Float16* __restrict__ Wtall,
                     const float* __restrict__ bq, const float* __restrict__ bk,
                     const float* __restrict__ bv,
                     _Float16* __restrict__ qo, _Float16* __restrict__ ko,
                     _Float16* __restrict__ vo, int M) {
    const _Float16* Wt; const float* bias; _Float16* out;
    if (blockIdx.z == 0)      { Wt = Wtall;                 bias = bq; out = qo; }
    else if (blockIdx.z == 1) { Wt = Wtall + 256 * 256;     bias = bk; out = ko; }
    else                      { Wt = Wtall + 2 * 256 * 256; bias = bv; out = vo; }
    mfma_gemm_body(A, Wt, bias, out, nullptr, M, blockIdx.x * 64, blockIdx.y * 64);
}

__global__ __launch_bounds__(256)
void wo_mfma_kernel(const _Float16* __restrict__ A,
                    const _Float16* __restrict__ Wtall,
                    const float* __restrict__ bo,
                    float* __restrict__ x2, int M) {
    mfma_gemm_body(A, Wtall + 3 * 256 * 256, bo, nullptr, x2, M,
                   blockIdx.x * 64, blockIdx.y * 64);
}

// ---------------------------------------------------------------------------
// K5: MFMA f16 flash attention. FTQ=32, FTK=64, 128 threads (2 waves);
// grid 29 x 16 = 464 blocks for full CU coverage. LDS ~14 KB.
// ---------------------------------------------------------------------------
static constexpr int FTQ = 32;
static constexpr int FTK = 64;

__global__ __launch_bounds__(128)
void flash_attn_mfma_kernel(const _Float16* __restrict__ qbuf,
                            const _Float16* __restrict__ kbuf,
                            const _Float16* __restrict__ vbuf,
                            _Float16* __restrict__ obuf) {
    __shared__ _Float16 Ks[FTK][40];      // [n][k]
    __shared__ _Float16 Vt[HD][72];       // [d][k]
    __shared__ _Float16 Ps[2][16][72];    // per-wave P in A-layout

    int bh = blockIdx.y;
    int b = bh / NH, h = bh % NH;
    int m0 = blockIdx.x * FTQ;
    int t = threadIdx.x;                  // 0..127
    int wave = t >> 6, lane = t & 63;
    int quad = lane >> 4, col = lane & 15;

    const float scale = 0.17677669529663687f;  // 1/sqrt(32)

    f16x8 qf;
    {
        int qrow = m0 + wave * 16 + col;
        if (qrow < Qn) {
            qf = *(const f16x8*)(qbuf + ((size_t)b * Qn + qrow) * En + h * HD + quad * 8);
        } else {
            #pragma unroll
            for (int j = 0; j < 8; j++) qf[j] = (_Float16)0.f;
        }
    }

    f32x4 o0 = {0.f, 0.f, 0.f, 0.f};
    f32x4 o1 = {0.f, 0.f, 0.f, 0.f};
    float mrow[4] = {-3e38f, -3e38f, -3e38f, -3e38f};
    float lrow[4] = {0.f, 0.f, 0.f, 0.f};

    int nstage = t >> 1;          // 0..63: staging row
    int koff = (t & 1) * 16;      // 0 or 16

    for (int n0 = 0; n0 < Qn; n0 += FTK) {
        {   // stage K (row-major) and V (transposed): 16 f16 each per thread
            int ng = n0 + nstage;
            f16x8 k0v, k1v, v0v, v1v;
            if (ng < Qn) {
                const _Float16* kp = kbuf + ((size_t)b * Qn + ng) * En + h * HD + koff;
                const _Float16* vp = vbuf + ((size_t)b * Qn + ng) * En + h * HD + koff;
                k0v = *(const f16x8*)kp;  k1v = *(const f16x8*)(kp + 8);
                v0v = *(const f16x8*)vp;  v1v = *(const f16x8*)(vp + 8);
            } else {
                #pragma unroll
                for (int j = 0; j < 8; j++) { k0v[j]=(_Float16)0.f; k1v[j]=(_Float16)0.f;
                                              v0v[j]=(_Float16)0.f; v1v[j]=(_Float16)0.f; }
            }
            *(f16x8*)&Ks[nstage][koff]     = k0v;
            *(f16x8*)&Ks[nstage][koff + 8] = k1v;
            #pragma unroll
            for (int j = 0; j < 8; j++) {
                Vt[koff + j][nstage]     = v0v[j];
                Vt[koff + 8 + j][nstage] = v1v[j];
            }
        }
        __syncthreads();

        // S tile: 16 rows x 64 cols via 4 MFMAs
        f32x4 S[4];
        #pragma unroll
        for (int c = 0; c < 4; c++) {
            f16x8 kf = *(const f16x8*)&Ks[c * 16 + col][quad * 8];
            f32x4 z = {0.f, 0.f, 0.f, 0.f};
            S[c] = __builtin_amdgcn_mfma_f32_16x16x32_f16(qf, kf, z, 0, 0, 0);
            S[c] *= scale;
        }
        if (n0 + FTK > Qn) {
            #pragma unroll
            for (int c = 0; c < 4; c++) {
                if (n0 + c * 16 + col >= Qn) {
                    S[c][0] = -3e38f; S[c][1] = -3e38f; S[c][2] = -3e38f; S[c][3] = -3e38f;
                }
            }
        }

        // online softmax per row (row = quad*4+r)
        float p[4][4];
        #pragma unroll
        for (int r = 0; r < 4; r++) {
            float mx = fmaxf(fmaxf(S[0][r], S[1][r]), fmaxf(S[2][r], S[3][r]));
            #pragma unroll
            for (int off = 8; off >= 1; off >>= 1)
                mx = fmaxf(mx, __shfl_xor(mx, off, 64));
            float mnew = fmaxf(mrow[r], mx);
            float alpha = __expf(mrow[r] - mnew);
            mrow[r] = mnew;
            float rs = 0.f;
            #pragma unroll
            for (int c = 0; c < 4; c++) {
                float pv = __expf(S[c][r] - mnew);
                p[c][r] = pv;
                rs += pv;
            }
            #pragma unroll
            for (int off = 8; off >= 1; off >>= 1)
                rs += __shfl_xor(rs, off, 64);
            lrow[r] = lrow[r] * alpha + rs;
            o0[r] *= alpha;
            o1[r] *= alpha;
        }

        // P: C-layout -> A-layout via per-wave LDS round trip
        #pragma unroll
        for (int c = 0; c < 4; c++)
            #pragma unroll
            for (int r = 0; r < 4; r++)
                Ps[wave][quad * 4 + r][c * 16 + col] = (_Float16)p[c][r];

        // PV: O += P(16x64) @ V(64x32)
        #pragma unroll
        for (int kc = 0; kc < 2; kc++) {
            f16x8 pf = *(const f16x8*)&Ps[wave][col][kc * 32 + quad * 8];
            f16x8 v0 = *(const f16x8*)&Vt[col][kc * 32 + quad * 8];
            f16x8 v1 = *(const f16x8*)&Vt[16 + col][kc * 32 + quad * 8];
            o0 = __builtin_amdgcn_mfma_f32_16x16x32_f16(pf, v0, o0, 0, 0, 0);
            o1 = __builtin_amdgcn_mfma_f32_16x16x32_f16(pf, v1, o1, 0, 0, 0);
        }
        __syncthreads();
    }

    #pragma unroll
    for (int r = 0; r < 4; r++) {
        int q = m0 + wave * 16 + quad * 4 + r;
        if (q < Qn) {
            float inv = 1.f / lrow[r];
            _Float16* op = obuf + ((size_t)b * Qn + q) * En + h * HD;
            op[col]      = (_Float16)(o0[r] * inv);
            op[16 + col] = (_Float16)(o1[r] * inv);
        }
    }
}

// ---------------------------------------------------------------------------
// K6: LN + box head, wave-per-row (barrier-free). Block = 4 waves = 4 rows;
// lane holds 4 channels (float4); LN via 64-lane shfl_xor; box weights read
// 160 B contiguous per lane (coalesced); lane0 writes the 10 outputs.
// ---------------------------------------------------------------------------
__global__ __launch_bounds__(256)
void ln_box_kernel(const float* __restrict__ x2,
                   const float* __restrict__ ln_g,
                   const float* __restrict__ ln_b,
                   const float* __restrict__ boxW,
                   const float* __restrict__ boxb,
                   float* __restrict__ outp, int M) {
    int t = threadIdx.x;
    int wave = t >> 6, lane = t & 63;
    int m = blockIdx.x * 4 + wave;
    if (m >= M) return;
    int k0 = lane * 4;

    float4 xv = *(const float4*)&x2[(size_t)m * En + k0];
    float sum = xv.x + xv.y + xv.z + xv.w;
    #pragma unroll
    for (int off = 32; off >= 1; off >>= 1) sum += __shfl_xor(sum, off, 64);
    float mu = sum * (1.f / 256.f);
    float d0 = xv.x - mu, d1 = xv.y - mu, d2 = xv.z - mu, d3 = xv.w - mu;
    float sq = d0 * d0 + d1 * d1 + d2 * d2 + d3 * d3;
    #pragma unroll
    for (int off = 32; off >= 1; off >>= 1) sq += __shfl_xor(sq, off, 64);
    float rstd = rsqrtf(sq * (1.f / 256.f) + 1e-5f);

    float4 gv = *(const float4*)&ln_g[k0];
    float4 bv = *(const float4*)&ln_b[k0];
    float y0 = d0 * rstd * gv.x + bv.x;
    float y1 = d1 * rstd * gv.y + bv.y;
    float y2 = d2 * rstd * gv.z + bv.z;
    float y3 = d3 * rstd * gv.w + bv.w;

    float pj[10];
    const float* wrow = boxW + (size_t)k0 * 10;
    #pragma unroll
    for (int j = 0; j < 10; j++)
        pj[j] = y0 * wrow[j] + y1 * wrow[10 + j] + y2 * wrow[20 + j] + y3 * wrow[30 + j];
    #pragma unroll
    for (int j = 0; j < 10; j++)
        #pragma unroll
        for (int off = 32; off >= 1; off >>= 1)
            pj[j] += __shfl_xor(pj[j], off, 64);
    if (lane == 0) {
        #pragma unroll
        for (int j = 0; j < 10; j++)
            outp[(size_t)m * 10 + j] = pj[j] + boxb[j];
    }
}

// ---------------------------------------------------------------------------
extern "C" void kernel_launch(void* const* d_in, const int* in_sizes, int n_in,
                              void* d_out, int out_size, void* d_ws, size_t ws_size,
                              hipStream_t stream) {
    const float* image_features = (const float*)d_in[0];
    const float* lidar2img      = (const float*)d_in[1];
    const float* query_table    = (const float*)d_in[2];
    const float* ref_W          = (const float*)d_in[3];
    const float* ref_b          = (const float*)d_in[4];
    const float* Wq             = (const float*)d_in[5];
    const float* bq             = (const float*)d_in[6];
    const float* Wk             = (const float*)d_in[7];
    const float* bk             = (const float*)d_in[8];
    const float* Wv             = (const float*)d_in[9];
    const float* bv             = (const float*)d_in[10];
    const float* Wo             = (const float*)d_in[11];
    const float* bo             = (const float*)d_in[12];
    const float* ln_g           = (const float*)d_in[13];
    const float* ln_b           = (const float*)d_in[14];
    const float* box_W          = (const float*)d_in[15];
    const float* box_b          = (const float*)d_in[16];
    float* out = (float*)d_out;

    char* ws = (char*)d_ws;
    size_t off = 0;
    auto alloc = [&](size_t bytes) { char* p = ws + off; off += (bytes + 255) & ~size_t(255); return p; };
    _Float16*  xbuf    = (_Float16*) alloc((size_t)Bv * Qn * En * 2);
    _Float16*  qbuf    = (_Float16*) alloc((size_t)Bv * Qn * En * 2);
    _Float16*  kbuf    = (_Float16*) alloc((size_t)Bv * Qn * En * 2);
    _Float16*  vbuf    = (_Float16*) alloc((size_t)Bv * Qn * En * 2);
    _Float16*  obuf    = (_Float16*) alloc((size_t)Bv * Qn * En * 2);
    float*     x2buf   = (float*)    alloc((size_t)Bv * Qn * En * 4);
    _Float16*  Wtall   = (_Float16*) alloc((size_t)4 * 256 * 256 * 2);

    float* out_ref3d = out + (size_t)Bv * Qn * 10;
    int M = Bv * Qn;  // 1800

    // K0: weight pack (f16, transposed)
    hipLaunchKernelGGL(wpack_kernel, dim3(256), dim3(256), 0, stream,
                       Wq, Wk, Wv, Wo, Wtall);

    // K3: fused ref3d + projection + bilinear sample + masked mean + add qe
    hipLaunchKernelGGL(sample_kernel, dim3(Bv * Qn), dim3(256), 0, stream,
                       image_features, query_table, ref_W, ref_b, lidar2img,
                       xbuf, out_ref3d);

    // K4: q/k/v projections (MFMA f16, fused)
    hipLaunchKernelGGL(qkv_mfma_kernel, dim3((M + 63) / 64, En / 64, 3), dim3(256),
                       0, stream, xbuf, Wtall, bq, bk, bv, qbuf, kbuf, vbuf, M);

    // K5: MFMA flash attention (FTQ=32, 2-wave blocks, 464 blocks)
    hipLaunchKernelGGL(flash_attn_mfma_kernel,
                       dim3((Qn + FTQ - 1) / FTQ, Bv * NH), dim3(128), 0, stream,
                       qbuf, kbuf, vbuf, obuf);

    // K6: o @ Wo + bo (MFMA f16, fp32 out)
    hipLaunchKernelGGL(wo_mfma_kernel, dim3((M + 63) / 64, En / 64), dim3(256),
                       0, stream, obuf, Wtall, bo, x2buf, M);

    // K7: LN + box head (wave-per-row, barrier-free, 450 blocks)
    hipLaunchKernelGGL(ln_box_kernel, dim3((M + 3) / 4), dim3(256), 0, stream,
                       x2buf, ln_g, ln_b, box_W, box_b, out, M);
}

// Round 10
// 171.132 us; speedup vs baseline: 1.0206x; 1.0206x over previous
//
#include <hip/hip_runtime.h>
#include <math.h>

// Problem constants
static constexpr int Bv  = 2;
static constexpr int Ncam= 6;
static constexpr int Cch = 256;
static constexpr int Hh  = 56;
static constexpr int Ww  = 100;
static constexpr int Pn  = Hh * Ww;  // 5600 flat pixels
static constexpr int Qn  = 900;
static constexpr int En  = 256;
static constexpr int NH  = 8;
static constexpr int HD  = 32;   // E / NH

typedef _Float16 f16x8 __attribute__((ext_vector_type(8)));
typedef _Float16 f16x4 __attribute__((ext_vector_type(4)));
typedef _Float16 f16x2 __attribute__((ext_vector_type(2)));
typedef float    f32x4 __attribute__((ext_vector_type(4)));

// ---------------------------------------------------------------------------
// K1 (fused prelude): blocks 0..255 = weight pack (4 x fp32[K][N] -> f16[N][K]);
// blocks 256..2055 = ref3d + projection + bilinear sample + masked mean + qe.
// The two halves are independent; fusing them overlaps the pack's streaming
// with the sample's latency-bound gather and removes one launch gap.
// ---------------------------------------------------------------------------
__global__ __launch_bounds__(256)
void pack_sample_kernel(const float* __restrict__ W0, const float* __restrict__ W1,
                        const float* __restrict__ W2, const float* __restrict__ W3,
                        _Float16* __restrict__ wt_out,
                        const float* __restrict__ feats,
                        const float* __restrict__ qt,
                        const float* __restrict__ refW,
                        const float* __restrict__ refb,
                        const float* __restrict__ l2i,
                        _Float16* __restrict__ xbuf,
                        float* __restrict__ out_ref3d) {
    __shared__ float smem[32 * 33];   // wpack tile; sample uses first 12 floats
    int bid = blockIdx.x;
    int t = threadIdx.x;

    if (bid < 256) {
        // ---- weight pack ----
        float (*tile)[33] = (float(*)[33])smem;
        int z = bid >> 6, rem = bid & 63;
        const float* src = (z == 0) ? W0 : (z == 1) ? W1 : (z == 2) ? W2 : W3;
        int k0 = (rem & 7) * 32, n0 = (rem >> 3) * 32;
        int tx = t & 31, ty = t >> 5;  // 32 x 8
        for (int i = 0; i < 32; i += 8)
            tile[ty + i][tx] = src[(size_t)(k0 + ty + i) * 256 + n0 + tx];
        __syncthreads();
        _Float16* dst = wt_out + (size_t)z * 256 * 256;
        for (int i = 0; i < 32; i += 8)
            dst[(size_t)(n0 + ty + i) * 256 + k0 + tx] = (_Float16)tile[tx][ty + i];
        return;
    }

    // ---- sample ----
    float (*red)[3] = (float(*)[3])smem;
    int bq = bid - 256;
    int b = bq / Qn, q = bq % Qn;
    int wave = t >> 6, lane = t & 63;
    int c = t;

    // ref3d: 256x3 dot + sigmoid
    float a = qt[(size_t)q * En + c];
    float s0 = a * refW[c * 3 + 0];
    float s1 = a * refW[c * 3 + 1];
    float s2 = a * refW[c * 3 + 2];
    #pragma unroll
    for (int off = 32; off >= 1; off >>= 1) {
        s0 += __shfl_xor(s0, off, 64);
        s1 += __shfl_xor(s1, off, 64);
        s2 += __shfl_xor(s2, off, 64);
    }
    if (lane == 0) { red[wave][0] = s0; red[wave][1] = s1; red[wave][2] = s2; }
    __syncthreads();
    float v0 = red[0][0] + red[1][0] + red[2][0] + red[3][0];
    float v1 = red[0][1] + red[1][1] + red[2][1] + red[3][1];
    float v2 = red[0][2] + red[1][2] + red[2][2] + red[3][2];
    v0 = 1.f / (1.f + __expf(-(v0 + refb[0])));
    v1 = 1.f / (1.f + __expf(-(v1 + refb[1])));
    v2 = 1.f / (1.f + __expf(-(v2 + refb[2])));
    if (b == 0 && t < 3) {
        float rv = (t == 0) ? v0 : (t == 1) ? v1 : v2;
        out_ref3d[(size_t)q * 3 + t] = rv;
        out_ref3d[(size_t)(Qn + q) * 3 + t] = rv;
    }

    // per-camera projection (wave-uniform) + gather
    float acc = 0.f, cnt = 0.f;
    for (int n = 0; n < Ncam; n++) {
        const float* M = l2i + (size_t)(b * Ncam + n) * 16;
        float p0 = M[0] * v0 + M[1] * v1 + M[2]  * v2 + M[3];
        float p1 = M[4] * v0 + M[5] * v1 + M[6]  * v2 + M[7];
        float z  = M[8] * v0 + M[9] * v1 + M[10] * v2 + M[11];
        float denom = fabsf(z) + 1e-5f;
        float px = p0 / denom, py = p1 / denom;
        float gx = px / (float)(Ww - 1) * 2.f - 1.f;
        float gy = py / (float)(Hh - 1) * 2.f - 1.f;
        bool zm = z > 1e-5f;
        bool valid = (gx > -1.f) && (gx < 1.f) && (gy > -1.f) && (gy < 1.f);
        if (zm && valid) {
            cnt += 1.f;
            float x = ((gx + 1.f) * (float)Ww - 1.f) * 0.5f;
            float y = ((gy + 1.f) * (float)Hh - 1.f) * 0.5f;
            float x0f = floorf(x), y0f = floorf(y);
            int x0 = (int)x0f, y0 = (int)y0f;
            float wx1 = x - x0f, wx0 = 1.f - wx1;
            float wy1 = y - y0f, wy0 = 1.f - wy1;
            const float* base = feats + ((size_t)(b * Ncam + n) * Cch + c) * Pn;
            if (x0 >= 0 && x0 + 1 < Ww && y0 >= 0 && y0 + 1 < Hh) {
                const float* r0 = base + (size_t)y0 * Ww + x0;
                const float* r1 = r0 + Ww;
                acc += r0[0] * (wx0 * wy0) + r0[1] * (wx1 * wy0)
                     + r1[0] * (wx0 * wy1) + r1[1] * (wx1 * wy1);
            } else {
                bool xin0 = (x0 >= 0) & (x0 < Ww), xin1 = (x0 + 1 >= 0) & (x0 + 1 < Ww);
                bool yin0 = (y0 >= 0) & (y0 < Hh), yin1 = (y0 + 1 >= 0) & (y0 + 1 < Hh);
                if (xin0 & yin0) acc += base[(size_t)y0 * Ww + x0]           * (wx0 * wy0);
                if (xin1 & yin0) acc += base[(size_t)y0 * Ww + x0 + 1]       * (wx1 * wy0);
                if (xin0 & yin1) acc += base[(size_t)(y0 + 1) * Ww + x0]     * (wx0 * wy1);
                if (xin1 & yin1) acc += base[(size_t)(y0 + 1) * Ww + x0 + 1] * (wx1 * wy1);
            }
        }
    }
    float tgt = acc / fmaxf(cnt, 1.f);
    xbuf[(size_t)bq * En + c] = (_Float16)(qt[(size_t)q * En + c] + tgt);
}

// ---------------------------------------------------------------------------
// K4: MFMA f16 GEMM body (64x64 tile): C = A @ Wt + bias; f16 or f32 out.
// ---------------------------------------------------------------------------
__device__ __forceinline__ void mfma_gemm_body(const _Float16* __restrict__ A,
                                               const _Float16* __restrict__ Wt,
                                               const float* __restrict__ bias,
                                               _Float16* __restrict__ Cf16,
                                               float* __restrict__ Cf32,
                                               int M, int m0, int n0) {
    __shared__ _Float16 Ws[64][264];
    int t = threadIdx.x;
    int wave = t >> 6, lane = t & 63, quad = lane >> 4, col = lane & 15;
    {
        int row = t >> 5;
        int off = (t & 31) * 8;
        for (int i = 0; i < 8; i++)
            *(f16x8*)&Ws[row + i * 8][off] =
                *(const f16x8*)&Wt[(size_t)(n0 + row + i * 8) * 256 + off];
    }
    f16x8 af[8];
    int mrow = m0 + wave * 16 + col;
    if (mrow < M) {
        const _Float16* ap = A + (size_t)mrow * 256 + quad * 8;
        #pragma unroll
        for (int kc = 0; kc < 8; kc++) af[kc] = *(const f16x8*)(ap + kc * 32);
    } else {
        #pragma unroll
        for (int kc = 0; kc < 8; kc++)
            #pragma unroll
            for (int j = 0; j < 8; j++) af[kc][j] = (_Float16)0.f;
    }
    __syncthreads();
    f32x4 acc[4];
    #pragma unroll
    for (int nt = 0; nt < 4; nt++) { acc[nt][0]=0.f; acc[nt][1]=0.f; acc[nt][2]=0.f; acc[nt][3]=0.f; }
    #pragma unroll
    for (int nt = 0; nt < 4; nt++)
        #pragma unroll
        for (int kc = 0; kc < 8; kc++) {
            f16x8 bf = *(const f16x8*)&Ws[nt * 16 + col][kc * 32 + quad * 8];
            acc[nt] = __builtin_amdgcn_mfma_f32_16x16x32_f16(af[kc], bf, acc[nt], 0, 0, 0);
        }
    #pragma unroll
    for (int nt = 0; nt < 4; nt++) {
        int n = n0 + nt * 16 + col;
        float bv = bias[n];
        #pragma unroll
        for (int r = 0; r < 4; r++) {
            int m = m0 + wave * 16 + quad * 4 + r;
            if (m < M) {
                float v = acc[nt][r] + bv;
                if (Cf16) Cf16[(size_t)m * 256 + n] = (_Float16)v;
                else      Cf32[(size_t)m * 256 + n] = v;
            }
        }
    }
}

__global__ __launch_bounds__(256)
void qkv_mfma_kernel(const _Float16* __restrict__ A,
                     const _Float16* __restrict__ Wtall,
                     const float* __restrict__ bq, const float* __restrict__ bk,
                     const float* __restrict__ bv,
                     _Float16* __restrict__ qo, _Float16* __restrict__ ko,
                     _Float16* __restrict__ vo, int M) {
    const _Float16* Wt; const float* bias; _Float16* out;
    if (blockIdx.z == 0)      { Wt = Wtall;                 bias = bq; out = qo; }
    else if (blockIdx.z == 1) { Wt = Wtall + 256 * 256;     bias = bk; out = ko; }
    else                      { Wt = Wtall + 2 * 256 * 256; bias = bv; out = vo; }
    mfma_gemm_body(A, Wt, bias, out, nullptr, M, blockIdx.x * 64, blockIdx.y * 64);
}

__global__ __launch_bounds__(256)
void wo_mfma_kernel(const _Float16* __restrict__ A,
                    const _Float16* __restrict__ Wtall,
                    const float* __restrict__ bo,
                    float* __restrict__ x2, int M) {
    mfma_gemm_body(A, Wtall + 3 * 256 * 256, bo, nullptr, x2, M,
                   blockIdx.x * 64, blockIdx.y * 64);
}

// ---------------------------------------------------------------------------
// K5: MFMA f16 flash attention. FTQ=32, FTK=64, 128 threads (2 waves);
// grid 29 x 16 = 464 blocks for full CU coverage. LDS ~14 KB.
// ---------------------------------------------------------------------------
static constexpr int FTQ = 32;
static constexpr int FTK = 64;

__global__ __launch_bounds__(128)
void flash_attn_mfma_kernel(const _Float16* __restrict__ qbuf,
                            const _Float16* __restrict__ kbuf,
                            const _Float16* __restrict__ vbuf,
                            _Float16* __restrict__ obuf) {
    __shared__ _Float16 Ks[FTK][40];      // [n][k]
    __shared__ _Float16 Vt[HD][72];       // [d][k]
    __shared__ _Float16 Ps[2][16][72];    // per-wave P in A-layout

    int bh = blockIdx.y;
    int b = bh / NH, h = bh % NH;
    int m0 = blockIdx.x * FTQ;
    int t = threadIdx.x;                  // 0..127
    int wave = t >> 6, lane = t & 63;
    int quad = lane >> 4, col = lane & 15;

    const float scale = 0.17677669529663687f;  // 1/sqrt(32)

    f16x8 qf;
    {
        int qrow = m0 + wave * 16 + col;
        if (qrow < Qn) {
            qf = *(const f16x8*)(qbuf + ((size_t)b * Qn + qrow) * En + h * HD + quad * 8);
        } else {
            #pragma unroll
            for (int j = 0; j < 8; j++) qf[j] = (_Float16)0.f;
        }
    }

    f32x4 o0 = {0.f, 0.f, 0.f, 0.f};
    f32x4 o1 = {0.f, 0.f, 0.f, 0.f};
    float mrow[4] = {-3e38f, -3e38f, -3e38f, -3e38f};
    float lrow[4] = {0.f, 0.f, 0.f, 0.f};

    int nstage = t >> 1;          // 0..63: staging row
    int koff = (t & 1) * 16;      // 0 or 16

    for (int n0 = 0; n0 < Qn; n0 += FTK) {
        {   // stage K (row-major) and V (transposed): 16 f16 each per thread
            int ng = n0 + nstage;
            f16x8 k0v, k1v, v0v, v1v;
            if (ng < Qn) {
                const _Float16* kp = kbuf + ((size_t)b * Qn + ng) * En + h * HD + koff;
                const _Float16* vp = vbuf + ((size_t)b * Qn + ng) * En + h * HD + koff;
                k0v = *(const f16x8*)kp;  k1v = *(const f16x8*)(kp + 8);
                v0v = *(const f16x8*)vp;  v1v = *(const f16x8*)(vp + 8);
            } else {
                #pragma unroll
                for (int j = 0; j < 8; j++) { k0v[j]=(_Float16)0.f; k1v[j]=(_Float16)0.f;
                                              v0v[j]=(_Float16)0.f; v1v[j]=(_Float16)0.f; }
            }
            *(f16x8*)&Ks[nstage][koff]     = k0v;
            *(f16x8*)&Ks[nstage][koff + 8] = k1v;
            #pragma unroll
            for (int j = 0; j < 8; j++) {
                Vt[koff + j][nstage]     = v0v[j];
                Vt[koff + 8 + j][nstage] = v1v[j];
            }
        }
        __syncthreads();

        // S tile: 16 rows x 64 cols via 4 MFMAs
        f32x4 S[4];
        #pragma unroll
        for (int c = 0; c < 4; c++) {
            f16x8 kf = *(const f16x8*)&Ks[c * 16 + col][quad * 8];
            f32x4 z = {0.f, 0.f, 0.f, 0.f};
            S[c] = __builtin_amdgcn_mfma_f32_16x16x32_f16(qf, kf, z, 0, 0, 0);
            S[c] *= scale;
        }
        if (n0 + FTK > Qn) {
            #pragma unroll
            for (int c = 0; c < 4; c++) {
                if (n0 + c * 16 + col >= Qn) {
                    S[c][0] = -3e38f; S[c][1] = -3e38f; S[c][2] = -3e38f; S[c][3] = -3e38f;
                }
            }
        }

        // online softmax per row (row = quad*4+r)
        float p[4][4];
        #pragma unroll
        for (int r = 0; r < 4; r++) {
            float mx = fmaxf(fmaxf(S[0][r], S[1][r]), fmaxf(S[2][r], S[3][r]));
            #pragma unroll
            for (int off = 8; off >= 1; off >>= 1)
                mx = fmaxf(mx, __shfl_xor(mx, off, 64));
            float mnew = fmaxf(mrow[r], mx);
            float alpha = __expf(mrow[r] - mnew);
            mrow[r] = mnew;
            float rs = 0.f;
            #pragma unroll
            for (int c = 0; c < 4; c++) {
                float pv = __expf(S[c][r] - mnew);
                p[c][r] = pv;
                rs += pv;
            }
            #pragma unroll
            for (int off = 8; off >= 1; off >>= 1)
                rs += __shfl_xor(rs, off, 64);
            lrow[r] = lrow[r] * alpha + rs;
            o0[r] *= alpha;
            o1[r] *= alpha;
        }

        // P: C-layout -> A-layout via per-wave LDS round trip
        #pragma unroll
        for (int c = 0; c < 4; c++)
            #pragma unroll
            for (int r = 0; r < 4; r++)
                Ps[wave][quad * 4 + r][c * 16 + col] = (_Float16)p[c][r];

        // PV: O += P(16x64) @ V(64x32)
        #pragma unroll
        for (int kc = 0; kc < 2; kc++) {
            f16x8 pf = *(const f16x8*)&Ps[wave][col][kc * 32 + quad * 8];
            f16x8 v0 = *(const f16x8*)&Vt[col][kc * 32 + quad * 8];
            f16x8 v1 = *(const f16x8*)&Vt[16 + col][kc * 32 + quad * 8];
            o0 = __builtin_amdgcn_mfma_f32_16x16x32_f16(pf, v0, o0, 0, 0, 0);
            o1 = __builtin_amdgcn_mfma_f32_16x16x32_f16(pf, v1, o1, 0, 0, 0);
        }
        __syncthreads();
    }

    #pragma unroll
    for (int r = 0; r < 4; r++) {
        int q = m0 + wave * 16 + quad * 4 + r;
        if (q < Qn) {
            float inv = 1.f / lrow[r];
            _Float16* op = obuf + ((size_t)b * Qn + q) * En + h * HD;
            op[col]      = (_Float16)(o0[r] * inv);
            op[16 + col] = (_Float16)(o1[r] * inv);
        }
    }
}

// ---------------------------------------------------------------------------
// K6: LN + box head, wave-per-row (barrier-free). Block = 4 waves = 4 rows.
// ---------------------------------------------------------------------------
__global__ __launch_bounds__(256)
void ln_box_kernel(const float* __restrict__ x2,
                   const float* __restrict__ ln_g,
                   const float* __restrict__ ln_b,
                   const float* __restrict__ boxW,
                   const float* __restrict__ boxb,
                   float* __restrict__ outp, int M) {
    int t = threadIdx.x;
    int wave = t >> 6, lane = t & 63;
    int m = blockIdx.x * 4 + wave;
    if (m >= M) return;
    int k0 = lane * 4;

    float4 xv = *(const float4*)&x2[(size_t)m * En + k0];
    float sum = xv.x + xv.y + xv.z + xv.w;
    #pragma unroll
    for (int off = 32; off >= 1; off >>= 1) sum += __shfl_xor(sum, off, 64);
    float mu = sum * (1.f / 256.f);
    float d0 = xv.x - mu, d1 = xv.y - mu, d2 = xv.z - mu, d3 = xv.w - mu;
    float sq = d0 * d0 + d1 * d1 + d2 * d2 + d3 * d3;
    #pragma unroll
    for (int off = 32; off >= 1; off >>= 1) sq += __shfl_xor(sq, off, 64);
    float rstd = rsqrtf(sq * (1.f / 256.f) + 1e-5f);

    float4 gv = *(const float4*)&ln_g[k0];
    float4 bv = *(const float4*)&ln_b[k0];
    float y0 = d0 * rstd * gv.x + bv.x;
    float y1 = d1 * rstd * gv.y + bv.y;
    float y2 = d2 * rstd * gv.z + bv.z;
    float y3 = d3 * rstd * gv.w + bv.w;

    float pj[10];
    const float* wrow = boxW + (size_t)k0 * 10;
    #pragma unroll
    for (int j = 0; j < 10; j++)
        pj[j] = y0 * wrow[j] + y1 * wrow[10 + j] + y2 * wrow[20 + j] + y3 * wrow[30 + j];
    #pragma unroll
    for (int j = 0; j < 10; j++)
        #pragma unroll
        for (int off = 32; off >= 1; off >>= 1)
            pj[j] += __shfl_xor(pj[j], off, 64);
    if (lane == 0) {
        #pragma unroll
        for (int j = 0; j < 10; j++)
            outp[(size_t)m * 10 + j] = pj[j] + boxb[j];
    }
}

// ---------------------------------------------------------------------------
extern "C" void kernel_launch(void* const* d_in, const int* in_sizes, int n_in,
                              void* d_out, int out_size, void* d_ws, size_t ws_size,
                              hipStream_t stream) {
    const float* image_features = (const float*)d_in[0];
    const float* lidar2img      = (const float*)d_in[1];
    const float* query_table    = (const float*)d_in[2];
    const float* ref_W          = (const float*)d_in[3];
    const float* ref_b          = (const float*)d_in[4];
    const float* Wq             = (const float*)d_in[5];
    const float* bq             = (const float*)d_in[6];
    const float* Wk             = (const float*)d_in[7];
    const float* bk             = (const float*)d_in[8];
    const float* Wv             = (const float*)d_in[9];
    const float* bv             = (const float*)d_in[10];
    const float* Wo             = (const float*)d_in[11];
    const float* bo             = (const float*)d_in[12];
    const float* ln_g           = (const float*)d_in[13];
    const float* ln_b           = (const float*)d_in[14];
    const float* box_W          = (const float*)d_in[15];
    const float* box_b          = (const float*)d_in[16];
    float* out = (float*)d_out;

    char* ws = (char*)d_ws;
    size_t off = 0;
    auto alloc = [&](size_t bytes) { char* p = ws + off; off += (bytes + 255) & ~size_t(255); return p; };
    _Float16*  xbuf    = (_Float16*) alloc((size_t)Bv * Qn * En * 2);
    _Float16*  qbuf    = (_Float16*) alloc((size_t)Bv * Qn * En * 2);
    _Float16*  kbuf    = (_Float16*) alloc((size_t)Bv * Qn * En * 2);
    _Float16*  vbuf    = (_Float16*) alloc((size_t)Bv * Qn * En * 2);
    _Float16*  obuf    = (_Float16*) alloc((size_t)Bv * Qn * En * 2);
    float*     x2buf   = (float*)    alloc((size_t)Bv * Qn * En * 4);
    _Float16*  Wtall   = (_Float16*) alloc((size_t)4 * 256 * 256 * 2);

    float* out_ref3d = out + (size_t)Bv * Qn * 10;
    int M = Bv * Qn;  // 1800

    // K1: weight pack + ref3d/projection/sample (fused, independent halves)
    hipLaunchKernelGGL(pack_sample_kernel, dim3(256 + Bv * Qn), dim3(256), 0, stream,
                       Wq, Wk, Wv, Wo, Wtall,
                       image_features, query_table, ref_W, ref_b, lidar2img,
                       xbuf, out_ref3d);

    // K2: q/k/v projections (MFMA f16, fused)
    hipLaunchKernelGGL(qkv_mfma_kernel, dim3((M + 63) / 64, En / 64, 3), dim3(256),
                       0, stream, xbuf, Wtall, bq, bk, bv, qbuf, kbuf, vbuf, M);

    // K3: MFMA flash attention (FTQ=32, 2-wave blocks, 464 blocks)
    hipLaunchKernelGGL(flash_attn_mfma_kernel,
                       dim3((Qn + FTQ - 1) / FTQ, Bv * NH), dim3(128), 0, stream,
                       qbuf, kbuf, vbuf, obuf);

    // K4: o @ Wo + bo (MFMA f16, fp32 out)
    hipLaunchKernelGGL(wo_mfma_kernel, dim3((M + 63) / 64, En / 64), dim3(256),
                       0, stream, obuf, Wtall, bo, x2buf, M);

    // K5: LN + box head (wave-per-row, barrier-free, 450 blocks)
    hipLaunchKernelGGL(ln_box_kernel, dim3((M + 3) / 4), dim3(256), 0, stream,
                       x2buf, ln_g, ln_b, box_W, box_b, out, M);
}